// Round 1
// baseline (492.144 us; speedup 1.0000x reference)
//
#include <hip/hip_runtime.h>

// Luong attention: B=4, Q=K=2048, D=1024, fp32 in/out.
// Fused flash-style, fp16 MFMA (16x16x32), fp32 accumulation + online softmax.
// BM=32 q-rows per workgroup, BN=32 k-tile, full-width (D=1024) LDS tiles.

#define SQ 2048
#define SK 2048
#define DD 1024
#define NB 4

#define BM 32
#define BN 32

#define QS 1032   // Qh row stride (f16 elems): 2064 B, 16B-aligned rows
#define VS 1032
#define PS 40     // Pt row stride: 80 B

typedef _Float16 f16;
typedef _Float16 f16x8 __attribute__((ext_vector_type(8)));
typedef _Float16 f16x4 __attribute__((ext_vector_type(4)));
typedef float f32x4 __attribute__((ext_vector_type(4)));

__device__ __forceinline__ float red16_max(float v){
  v = fmaxf(v, __shfl_xor(v, 1, 64));
  v = fmaxf(v, __shfl_xor(v, 2, 64));
  v = fmaxf(v, __shfl_xor(v, 4, 64));
  v = fmaxf(v, __shfl_xor(v, 8, 64));
  return v;
}
__device__ __forceinline__ float red16_sum(float v){
  v += __shfl_xor(v, 1, 64);
  v += __shfl_xor(v, 2, 64);
  v += __shfl_xor(v, 4, 64);
  v += __shfl_xor(v, 8, 64);
  return v;
}

__global__ __launch_bounds__(256, 1)
void luong_attn(const float* __restrict__ Qg, const float* __restrict__ Vg,
                float* __restrict__ Og)
{
  extern __shared__ char smem[];
  f16*   Qh     = (f16*)smem;                 // [32][QS]
  f16*   Vh     = Qh + 32*QS;                 // [32][VS]
  f16*   Pt     = Vh + 32*VS;                 // [32][PS]
  float* pmax   = (float*)(Pt + 32*PS);       // [32][2]
  float* psum   = pmax + 64;                  // [32][2]
  float* mstate = psum + 64;                  // [32]
  float* lstate = mstate + 32;                // [32]
  float* alphas = lstate + 32;                // [32]

  const int tid  = threadIdx.x;
  const int wave = tid >> 6;       // 0..3
  const int lane = tid & 63;
  const int l16  = lane & 15;
  const int quad = lane >> 4;      // 0..3

  const int b  = blockIdx.x >> 6;  // 0..3
  const int qt = blockIdx.x & 63;  // 0..63
  const int q0 = qt * BM;

  if (tid < 32){ mstate[tid] = -3.0e30f; lstate[tid] = 0.0f; }

  // ---- stage Q tile (32 x 1024 fp32 -> fp16), once ----
  {
    const float4* src = (const float4*)(Qg + ((size_t)b*SQ + q0)*DD);
    #pragma unroll 8
    for (int i = 0; i < 32; ++i){
      float4 w = src[i*(DD/4) + tid];
      f16x4 h = { (f16)w.x, (f16)w.y, (f16)w.z, (f16)w.w };
      *(f16x4*)(Qh + i*QS + tid*4) = h;
    }
  }
  __syncthreads();

  const int rb_s = wave >> 1;   // score-phase row block (0/1)
  const int cb_s = wave & 1;    // score-phase col block (0/1)

  // O accumulator: this wave owns cols [wave*256, wave*256+256), all 32 rows.
  f32x4 o[2][16];
  #pragma unroll
  for (int r = 0; r < 2; ++r)
    #pragma unroll
    for (int t = 0; t < 16; ++t)
      o[r][t] = (f32x4){0.f, 0.f, 0.f, 0.f};

  const float4* vsrc = (const float4*)(Vg + (size_t)b*SK*DD);
  const float L2E = 1.44269504f;

  for (int kt = 0; kt < SK/BN; ++kt){
    // ---- stage V tile (32 x 1024 fp32 -> fp16) ----
    {
      const float4* src = vsrc + (size_t)kt*BN*(DD/4);
      #pragma unroll 8
      for (int i = 0; i < 32; ++i){
        float4 w = src[i*(DD/4) + tid];
        f16x4 h = { (f16)w.x, (f16)w.y, (f16)w.z, (f16)w.w };
        *(f16x4*)(Vh + i*VS + tid*4) = h;
      }
    }
    __syncthreads();  // (1) V staged

    // ---- scores: each wave computes 16x16 quadrant (rb_s, cb_s) over full D ----
    f32x4 sacc[4];
    #pragma unroll
    for (int i = 0; i < 4; ++i) sacc[i] = (f32x4){0.f,0.f,0.f,0.f};
    {
      const f16* qb = Qh + (rb_s*16 + l16)*QS + quad*8;
      const f16* vb = Vh + (cb_s*16 + l16)*VS + quad*8;
      #pragma unroll 8
      for (int dc = 0; dc < 32; ++dc){
        f16x8 a  = *(const f16x8*)(qb + dc*32);
        f16x8 bb = *(const f16x8*)(vb + dc*32);
        sacc[dc & 3] = __builtin_amdgcn_mfma_f32_16x16x32_f16(a, bb, sacc[dc & 3], 0, 0, 0);
      }
    }
    f32x4 s = sacc[0] + sacc[1] + sacc[2] + sacc[3];
    // S element: row = rb_s*16 + quad*4 + c, kcol = cb_s*16 + l16

    // ---- online softmax ----
    #pragma unroll
    for (int c = 0; c < 4; ++c){
      float mp = red16_max(s[c]);
      if (l16 == 0) pmax[(rb_s*16 + quad*4 + c)*2 + cb_s] = mp;
    }
    __syncthreads();  // (2)

    float mnew_c[4], alpha_c[4], psum_c[4];
    #pragma unroll
    for (int c = 0; c < 4; ++c){
      int row = rb_s*16 + quad*4 + c;
      float mold = mstate[row];
      float mnew = fmaxf(fmaxf(pmax[row*2], pmax[row*2+1]), mold);
      mnew_c[c]  = mnew;
      alpha_c[c] = exp2f((mold - mnew)*L2E);
      float p    = exp2f((s[c] - mnew)*L2E);
      psum_c[c]  = red16_sum(p);
      Pt[row*PS + cb_s*16 + l16] = (f16)p;
    }
    if (l16 == 0){
      #pragma unroll
      for (int c = 0; c < 4; ++c)
        psum[(rb_s*16 + quad*4 + c)*2 + cb_s] = psum_c[c];
    }
    __syncthreads();  // (3) psum/Pt visible; all mstate reads done

    if (cb_s == 0 && l16 == 0){
      #pragma unroll
      for (int c = 0; c < 4; ++c){
        int row = rb_s*16 + quad*4 + c;
        mstate[row] = mnew_c[c];
        alphas[row] = alpha_c[c];
        lstate[row] = lstate[row]*alpha_c[c] + psum[row*2] + psum[row*2+1];
      }
    }
    __syncthreads();  // (4) alphas visible

    // ---- rescale O by alpha ----
    float av[2][4];
    #pragma unroll
    for (int r = 0; r < 2; ++r)
      #pragma unroll
      for (int c = 0; c < 4; ++c)
        av[r][c] = alphas[r*16 + quad*4 + c];
    #pragma unroll
    for (int r = 0; r < 2; ++r)
      #pragma unroll
      for (int t = 0; t < 16; ++t)
        #pragma unroll
        for (int c = 0; c < 4; ++c)
          o[r][t][c] *= av[r][c];

    // ---- PV: O[rows][wave*256 + t*16 + l16] += P(32 wide) * V ----
    f16x8 ap0 = *(const f16x8*)(Pt + (0*16 + l16)*PS + quad*8);
    f16x8 ap1 = *(const f16x8*)(Pt + (1*16 + l16)*PS + quad*8);
    const f16* vb2 = Vh + wave*256 + l16;
    #pragma unroll
    for (int t = 0; t < 16; ++t){
      f16x8 bv;
      #pragma unroll
      for (int jj = 0; jj < 8; ++jj)
        bv[jj] = vb2[(quad*8 + jj)*VS + t*16];   // V[j][dcol], strided u16 reads
      o[0][t] = __builtin_amdgcn_mfma_f32_16x16x32_f16(ap0, bv, o[0][t], 0, 0, 0);
      o[1][t] = __builtin_amdgcn_mfma_f32_16x16x32_f16(ap1, bv, o[1][t], 0, 0, 0);
    }
    __syncthreads();  // (5) Vh/Pt free for next iteration
  }

  // ---- epilogue: O / l ----
  float linv[2][4];
  #pragma unroll
  for (int r = 0; r < 2; ++r)
    #pragma unroll
    for (int c = 0; c < 4; ++c)
      linv[r][c] = 1.0f / lstate[r*16 + quad*4 + c];

  float* outp = Og + ((size_t)b*SQ + q0)*DD;
  #pragma unroll
  for (int r = 0; r < 2; ++r)
    #pragma unroll
    for (int t = 0; t < 16; ++t)
      #pragma unroll
      for (int c = 0; c < 4; ++c){
        int row = r*16 + quad*4 + c;
        int col = wave*256 + t*16 + l16;
        outp[(size_t)row*DD + col] = o[r][t][c] * linv[r][c];
      }
}

extern "C" void kernel_launch(void* const* d_in, const int* in_sizes, int n_in,
                              void* d_out, int out_size, void* d_ws, size_t ws_size,
                              hipStream_t stream)
{
  const float* Qg = (const float*)d_in[0];
  const float* Vg = (const float*)d_in[1];
  float* Og = (float*)d_out;

  size_t smem = (size_t)(32*QS + 32*VS + 32*PS)*sizeof(f16)
              + (size_t)(64 + 64 + 32 + 32 + 32)*sizeof(float);

  // gfx950 has 160 KiB LDS/CU; opt in to >64 KiB dynamic LDS. Some ROCm
  // versions don't require this call — ignore its return value.
  (void)hipFuncSetAttribute(reinterpret_cast<const void*>(luong_attn),
                            hipFuncAttributeMaxDynamicSharedMemorySize,
                            (int)smem);

  dim3 grid(NB * (SQ / BM));   // 256 workgroups = 1 per CU
  dim3 block(256);             // 4 waves
  luong_attn<<<grid, block, smem, stream>>>(Qg, Vg, Og);
}